// Round 12
// baseline (101.989 us; speedup 1.0000x reference)
//
#include <hip/hip_runtime.h>

#define NN 4
#define CC 32
#define LL 8
#define DD 24
#define HH 24
#define WW 24

typedef short  bf16x8  __attribute__((ext_vector_type(8)));
typedef float  f32x16  __attribute__((ext_vector_type(16)));
typedef unsigned short ushort8 __attribute__((ext_vector_type(8)));

// ws layout (36,161,536 B):
//   xp: [cig 2][n 4][l 8][dp 26][hp 26][wp 26][ci16 -> 2 g-chunks] bf16
//   Ag: [cig 2][ql 3][qd 3][s 9][lane 64][j 8] bf16 (flipped wgt, frag order)
#define XP_CHUNKS 2249728            // 16B chunks
#define XP_ELEMS  (XP_CHUNKS * 8)
#define AG_ELEMS  82944

__device__ __forceinline__ unsigned short f2bf(float f) {
    union { float f; unsigned u; } v; v.f = f;
    unsigned r = v.u + 0x7FFFu + ((v.u >> 16) & 1u);   // RNE
    return (unsigned short)(r >> 16);
}

__device__ __forceinline__ void gload16(const void* g, void* l) {
    __builtin_amdgcn_global_load_lds(
        (const __attribute__((address_space(1))) unsigned int*)g,
        (__attribute__((address_space(3))) unsigned int*)l, 16, 0, 0);
}

// ---- fused pre-pass: x -> xp and wgt -> Ag (verified R5-R11) ----
__global__ __launch_bounds__(256) void prep(const float* __restrict__ x,
                                            const float* __restrict__ wgt,
                                            unsigned short* __restrict__ xp,
                                            unsigned short* __restrict__ Ag) {
    const int id = blockIdx.x * 256 + threadIdx.x;
    if (id < XP_CHUNKS) {
        const int wp = id % 26;
        const int r  = id / 26;
        const int g  = r & 1;
        const int r2 = r >> 1;             // slab*26 + hp
        const int hp = r2 % 26;
        const int slab = r2 / 26;          // ((cig*4 + n)*8 + l)*26 + dp
        const int dp = slab % 26;
        const int s2 = slab / 26;
        const int l  = s2 & 7;
        const int n  = (s2 >> 3) & 3;
        const int cig = s2 >> 5;
        const int dx = dp - 1, hx = hp - 1, wx = wp - 1;
        ushort8 v = {0, 0, 0, 0, 0, 0, 0, 0};
        if ((unsigned)dx < DD && (unsigned)hx < HH && (unsigned)wx < WW) {
            const int ci0 = cig * 16 + g * 8;
            const float* src = x + ((((size_t)n * CC + ci0) * LL + l) * DD + dx) * (HH * WW)
                             + hx * WW + wx;
#pragma unroll
            for (int ci = 0; ci < 8; ++ci)
                v[ci] = f2bf(src[(size_t)ci * (LL * DD * HH * WW)]);
        }
        const size_t dstc = ((size_t)r2 * 26 + wp) * 2 + g;
        *reinterpret_cast<ushort8*>(xp + dstc * 8) = v;
    } else {
        const int i = id - XP_CHUNKS;
        if (i < AG_ELEMS) {
            const int j  = i & 7;
            const int ln = (i >> 3) & 63;
            const int rest = i >> 9;       // 0..161
            const int s  = rest % 9;
            const int r  = rest / 9;       // cig*9 + ql*3 + qd
            const int qd = r % 3;
            const int ql = (r / 3) % 3;
            const int cig = r / 9;
            const int co = ln & 31, gg = ln >> 5;
            const int ci = cig * 16 + gg * 8 + j;
            const int tap = ql * 27 + qd * 9 + s;
            Ag[i] = f2bf(wgt[((size_t)ci * CC + co) * 81 + 80 - tap]);
        }
    }
}

// GEMM: A[co][k]=flipped wgt (M=32), B[k][pos]=shifted x, K=(ci,tap)=2592.
// K-step = 16 ci x 1 tap -> zero dummy MFMAs. Block=(n,l,d), 6 waves.
// LDS plane layout: [row 26][g 2][wp 27(26+pad)] 16B units, 54-unit rows.
// Lane stride = 1 unit and 54%8=6 -> every quarter-wave's b128 covers all
// 8 bank-quads exactly twice = conflict-FREE (fixes R11's 4-way conflict
// from the [wp][g] 2-unit stride). A: global->VGPR, pinned before the
// prefetch so the MFMA's vmcnt wait leaves the prefetch in flight.
__global__ __launch_bounds__(384) void convt4d_main(
    const unsigned short* __restrict__ xp, const unsigned short* __restrict__ Ag,
    const float* __restrict__ bias, float* __restrict__ out)
{
    __shared__ __align__(16) unsigned short xs[2][1404 * 8];   // 2 x 22,464 B

    // XCD-aware bijective swizzle (768 % 8 == 0)
    int bid = (int)blockIdx.x;
    bid = (bid & 7) * 96 + (bid >> 3);
    const int n = bid / (LL * DD);
    const int l = (bid / DD) % LL;
    const int d = bid % DD;

    const int t    = (int)threadIdx.x;
    const int lane = t & 63;
    const int wave = t >> 6;           // 0..5
    const int g    = lane >> 5;        // ci-half selector
    const int dh   = (lane >> 3) & 3;
    const int dw   = lane & 7;
    const int h0   = wave * 4;

    const int ql0 = (l == 0) ? 1 : 0;
    const int nql = 3 - (l == 0) - (l == 7);
    const int nst = 6 * nql;           // stages: (cig2, valid ql, qd3)

    f32x16 acc[3];
#pragma unroll
    for (int i = 0; i < 3; ++i)
#pragma unroll
        for (int j = 0; j < 16; ++j) acc[i][j] = 0.f;

    // per-lane ds_read base (shorts): unit = row*54 + g*27 + dw
    const int eb = ((h0 + dh) * 54 + g * 27 + dw) * 8;

    auto issueX = [&](int st, int buf) {
        const int qd  = st % 3;
        const int r   = st / 3;
        const int ql  = ql0 + r % nql;
        const int cig = r / nql;
        const int lx  = l + ql - 1;
        const size_t base = ((size_t)(((cig * 4 + n) * 8 + lx) * 26) + (d + qd)) * 1352;
        unsigned short* dst = xs[buf];
        // linear LDS dst (v*16B); source permutation injects the [g][wp]
        // 54-unit row layout: v -> row=v/54, g2=(v%54)/27, wp=(v%54)%27
#pragma unroll
        for (int k = 0; k < 4; ++k) {
            const int v = t + k * 384;
            if (k < 3 || v < 1404) {
                int row = v / 54;
                int rem = v - row * 54;
                int g2  = (rem >= 27) ? 1 : 0;
                int wp  = rem - g2 * 27;
                if (wp > 25) wp = 25;          // pad col: garbage, never read
                gload16(xp + (base + (size_t)(row * 26 + wp) * 2 + g2) * 8,
                        (char*)dst + (size_t)v * 16);
            }
        }
    };

    issueX(0, 0);

#pragma unroll 1
    for (int st = 0; st < nst; ++st) {
        const int buf = st & 1;
        __syncthreads();               // stage st landed; xs[buf^1] free

        // ---- A fragments for stage st: global->VGPR, issued FIRST so the
        //      MFMA's vmcnt wait on A leaves the prefetch in flight ----
        const int qd  = st % 3;
        const int r   = st / 3;
        const int ql  = ql0 + r % nql;
        const int cig = r / nql;
        const unsigned short* ab =
            Ag + (size_t)(cig * 9 + ql * 3 + qd) * 4608 + lane * 8;
        bf16x8 A[9];
#pragma unroll
        for (int s = 0; s < 9; ++s)
            A[s] = *reinterpret_cast<const bf16x8*>(ab + s * 512);
        __builtin_amdgcn_sched_barrier(0);   // pin: A-loads before prefetch

        if (st + 1 < nst) issueX(st + 1, buf ^ 1);
        __builtin_amdgcn_sched_barrier(0);   // pin: prefetch issued before compute

        // ---- 9 k-steps (taps) x 3 n-tiles; B from LDS, A from regs ----
        const unsigned short* xb = xs[buf] + eb;
        __builtin_amdgcn_s_setprio(1);
#pragma unroll
        for (int s = 0; s < 9; ++s) {
            const int qh = s / 3, qw = s % 3;
            const int o = (qh * 54 + qw) * 8;        // compile-time imm (shorts)
#pragma unroll
            for (int nt = 0; nt < 3; ++nt) {
                bf16x8 b = *reinterpret_cast<const bf16x8*>(xb + o + nt * 64);
                acc[nt] = __builtin_amdgcn_mfma_f32_32x32x16_bf16(A[s], b, acc[nt], 0, 0, 0);
            }
        }
        __builtin_amdgcn_s_setprio(0);
    }

    // ---- epilogue: bias + store (C/D: col=lane&31 -> pos, row -> co) ----
#pragma unroll
    for (int r = 0; r < 16; ++r) {
        const int co = (r & 3) + 8 * (r >> 2) + 4 * g;
        const float bv = bias[co];
        size_t ob = (((((size_t)n * CC + co) * LL + l) * DD + d) * HH + (h0 + dh)) * WW + dw;
        out[ob]      = acc[0][r] + bv;
        out[ob + 8]  = acc[1][r] + bv;
        out[ob + 16] = acc[2][r] + bv;
    }
}

extern "C" void kernel_launch(void* const* d_in, const int* in_sizes, int n_in,
                              void* d_out, int out_size, void* d_ws, size_t ws_size,
                              hipStream_t stream) {
    const float* x    = (const float*)d_in[0];
    const float* wgt  = (const float*)d_in[1];
    const float* bias = (const float*)d_in[2];
    float* out = (float*)d_out;

    unsigned short* xp = (unsigned short*)d_ws;
    unsigned short* Ag = xp + XP_ELEMS;

    prep<<<(XP_CHUNKS + AG_ELEMS) / 256, 256, 0, stream>>>(x, wgt, xp, Ag);  // 9112 blocks
    convt4d_main<<<NN * LL * DD, 384, 0, stream>>>(xp, Ag, bias, out);
}